// Round 1
// baseline (495.665 us; speedup 1.0000x reference)
//
#include <hip/hip_runtime.h>

#define EPS 1e-5f

typedef __bf16 bf16x8 __attribute__((ext_vector_type(8)));
typedef float f32x4 __attribute__((ext_vector_type(4)));

union BF8 { bf16x8 v; unsigned short u[8]; };

__device__ inline unsigned short f32_to_bf16(float f) {
    unsigned u = __builtin_bit_cast(unsigned, f);
    return (unsigned short)((u + 0x7FFFu + ((u >> 16) & 1u)) >> 16);
}
__device__ inline float bf16_lo(unsigned u) { return __builtin_bit_cast(float, u << 16); }
__device__ inline float bf16_hi(unsigned u) { return __builtin_bit_cast(float, u & 0xFFFF0000u); }
__device__ inline float relu6f(float x) { return fminf(fmaxf(x, 0.f), 6.f); }

// ---------------- K1: x1 = relu6(bn1(feats @ W1)), stored bf16 ----------------
// block = 256 (4 waves), 64 rows/block, each wave one 16-row MFMA tile.
__global__ __launch_bounds__(256) void k1_expand(
    const float* __restrict__ feats, const float* __restrict__ W1,
    const float* __restrict__ g1, const float* __restrict__ b1,
    const float* __restrict__ m1, const float* __restrict__ v1,
    unsigned short* __restrict__ x1, int N)
{
    const int lane = threadIdx.x & 63;
    const int wave = threadIdx.x >> 6;
    const int m = lane & 15;   // A row / B col / C col
    const int q = lane >> 4;   // k-quad
    const int rowbase = blockIdx.x * 64 + wave * 16;

    // B fragments: B[k][n] with k = q*8+j, n = 16t+m  -> W1[k*192 + 16t+m]
    bf16x8 bfrag[12];
#pragma unroll
    for (int t = 0; t < 12; ++t) {
        BF8 tmp;
#pragma unroll
        for (int j = 0; j < 8; ++j)
            tmp.u[j] = f32_to_bf16(W1[(q * 8 + j) * 192 + 16 * t + m]);
        bfrag[t] = tmp.v;
    }

    // A fragment: A[m][k] = feats[rowbase+m][q*8+j]
    BF8 af;
    {
        int arow = rowbase + m;
        if (arow < N) {
            const float4* fp = (const float4*)(feats + arow * 32 + q * 8);
            float4 f0 = fp[0], f1 = fp[1];
            af.u[0] = f32_to_bf16(f0.x); af.u[1] = f32_to_bf16(f0.y);
            af.u[2] = f32_to_bf16(f0.z); af.u[3] = f32_to_bf16(f0.w);
            af.u[4] = f32_to_bf16(f1.x); af.u[5] = f32_to_bf16(f1.y);
            af.u[6] = f32_to_bf16(f1.z); af.u[7] = f32_to_bf16(f1.w);
        } else {
#pragma unroll
            for (int j = 0; j < 8; ++j) af.u[j] = 0;
        }
    }

    const f32x4 zero = {0.f, 0.f, 0.f, 0.f};
#pragma unroll
    for (int t = 0; t < 12; ++t) {
        f32x4 acc = __builtin_amdgcn_mfma_f32_16x16x32_bf16(af.v, bfrag[t], zero, 0, 0, 0);
        int c = 16 * t + m;                      // C col = lane&15
        float s  = g1[c] * rsqrtf(v1[c] + EPS);
        float bb = b1[c] - m1[c] * s;
#pragma unroll
        for (int i = 0; i < 4; ++i) {            // C row = q*4+i
            int r = rowbase + q * 4 + i;
            if (r < N) x1[r * 192 + c] = f32_to_bf16(relu6f(fmaf(acc[i], s, bb)));
        }
    }
}

// ------- K2: fused depthwise gather + bn2 + relu6 + project GEMM + bn3 + residual -------
// block = 192 (3 waves), 48 rows/block. x2 tile lives only in LDS (stride 200 bf16: the
// b128 A-frag reads then hit every bank exactly 8x -> conflict-free).
__global__ __launch_bounds__(192) void k2_fused(
    const unsigned short* __restrict__ x1, const int* __restrict__ nbr,
    const float* __restrict__ W2, const float* __restrict__ W3,
    const float* __restrict__ g2, const float* __restrict__ b2,
    const float* __restrict__ m2, const float* __restrict__ v2,
    const float* __restrict__ g3, const float* __restrict__ b3,
    const float* __restrict__ m3, const float* __restrict__ v3,
    const float* __restrict__ feats, float* __restrict__ out, int N)
{
    __shared__ __align__(16) unsigned short x2L[48 * 200];
    const int tid = threadIdx.x;
    const int rowbase = blockIdx.x * 48;

    // ---- phase A: depthwise sparse conv, thread owns one fixed h-pair ----
    {
        const int h2 = tid % 96;
        const int half = tid / 96;
        const int h = 2 * h2;
        float w2a[9], w2b[9];
#pragma unroll
        for (int k = 0; k < 9; ++k) {
            w2a[k] = W2[k * 192 + h];
            w2b[k] = W2[k * 192 + h + 1];
        }
        float sa = g2[h] * rsqrtf(v2[h] + EPS);
        float ba = b2[h] - m2[h] * sa;
        float sb = g2[h + 1] * rsqrtf(v2[h + 1] + EPS);
        float bbv = b2[h + 1] - m2[h + 1] * sb;
        for (int it = 0; it < 24; ++it) {
            int r = 2 * it + half;               // 0..47, each (r,h2) exactly once
            int n = rowbase + r;
            float a0 = 0.f, a1 = 0.f;
            if (n < N) {
                const int* nb = nbr + n * 9;
#pragma unroll
                for (int k = 0; k < 9; ++k) {
                    int idx = nb[k];             // row-uniform branch: cheap
                    if (idx >= 0) {
                        unsigned u = *(const unsigned*)(x1 + idx * 192 + h);
                        a0 = fmaf(bf16_lo(u), w2a[k], a0);
                        a1 = fmaf(bf16_hi(u), w2b[k], a1);
                    }
                }
            }
            unsigned pk = (unsigned)f32_to_bf16(relu6f(fmaf(a0, sa, ba)))
                        | ((unsigned)f32_to_bf16(relu6f(fmaf(a1, sb, bbv))) << 16);
            *(unsigned*)(&x2L[r * 200 + h]) = pk;
        }
    }
    __syncthreads();

    // ---- phase B: [48x192] @ [192x32] via MFMA, wave w -> rows 16w..16w+15 ----
    const int lane = tid & 63;
    const int wave = tid >> 6;
    const int m = lane & 15;
    const int q = lane >> 4;

    bf16x8 bfrag[12];                            // W3 B-frags: k = 32s+q*8+j, n = 16t+m
#pragma unroll
    for (int s = 0; s < 6; ++s)
#pragma unroll
        for (int t = 0; t < 2; ++t) {
            BF8 tmp;
#pragma unroll
            for (int j = 0; j < 8; ++j)
                tmp.u[j] = f32_to_bf16(W3[(32 * s + q * 8 + j) * 32 + 16 * t + m]);
            bfrag[s * 2 + t] = tmp.v;
        }

    f32x4 acc0 = {0.f, 0.f, 0.f, 0.f}, acc1 = {0.f, 0.f, 0.f, 0.f};
    const int rw = wave * 16;
#pragma unroll
    for (int s = 0; s < 6; ++s) {
        // A-frag: x2L[(rw+m)][32s + q*8 + j], 16B aligned (400 | 16, 64s+16q | 16)
        bf16x8 a = *reinterpret_cast<const bf16x8*>(&x2L[(rw + m) * 200 + 32 * s + q * 8]);
        acc0 = __builtin_amdgcn_mfma_f32_16x16x32_bf16(a, bfrag[s * 2 + 0], acc0, 0, 0, 0);
        acc1 = __builtin_amdgcn_mfma_f32_16x16x32_bf16(a, bfrag[s * 2 + 1], acc1, 0, 0, 0);
    }

#pragma unroll
    for (int t = 0; t < 2; ++t) {
        f32x4 acc = (t == 0) ? acc0 : acc1;
        int c = 16 * t + m;
        float s3  = g3[c] * rsqrtf(v3[c] + EPS);
        float bb3 = b3[c] - m3[c] * s3;
#pragma unroll
        for (int i = 0; i < 4; ++i) {
            int r = rowbase + rw + q * 4 + i;
            if (r < N) {
                int o = r * 32 + c;
                out[o] = fmaf(acc[i], s3, bb3) + feats[o];
            }
        }
    }
}

extern "C" void kernel_launch(void* const* d_in, const int* in_sizes, int n_in,
                              void* d_out, int out_size, void* d_ws, size_t ws_size,
                              hipStream_t stream) {
    const float* feats = (const float*)d_in[0];
    const int*   nbr   = (const int*)d_in[1];
    const float* W1    = (const float*)d_in[2];
    const float* W2    = (const float*)d_in[3];
    const float* W3    = (const float*)d_in[4];
    const float* g1 = (const float*)d_in[5];
    const float* b1 = (const float*)d_in[6];
    const float* m1 = (const float*)d_in[7];
    const float* v1 = (const float*)d_in[8];
    const float* g2 = (const float*)d_in[9];
    const float* b2 = (const float*)d_in[10];
    const float* m2 = (const float*)d_in[11];
    const float* v2 = (const float*)d_in[12];
    const float* g3 = (const float*)d_in[13];
    const float* b3 = (const float*)d_in[14];
    const float* m3 = (const float*)d_in[15];
    const float* v3 = (const float*)d_in[16];
    float* out = (float*)d_out;

    const int N = in_sizes[0] / 32;
    unsigned short* x1 = (unsigned short*)d_ws;   // N*192 bf16 = 76.8 MB

    k1_expand<<<dim3((N + 63) / 64), dim3(256), 0, stream>>>(
        feats, W1, g1, b1, m1, v1, x1, N);
    k2_fused<<<dim3((N + 47) / 48), dim3(192), 0, stream>>>(
        x1, nbr, W2, W3, g2, b2, m2, v2, g3, b3, m3, v3, feats, out, N);
}

// Round 2
// 365.455 us; speedup vs baseline: 1.3563x; 1.3563x over previous
//
#include <hip/hip_runtime.h>

#define EPS 1e-5f

typedef __bf16 bf16x8 __attribute__((ext_vector_type(8)));
typedef float f32x4 __attribute__((ext_vector_type(4)));

union BF8 { bf16x8 v; unsigned short u[8]; };

__device__ inline unsigned short f32_to_bf16(float f) {
    unsigned u = __builtin_bit_cast(unsigned, f);
    return (unsigned short)((u + 0x7FFFu + ((u >> 16) & 1u)) >> 16);
}
__device__ inline float bf16_lo(unsigned u) { return __builtin_bit_cast(float, u << 16); }
__device__ inline float bf16_hi(unsigned u) { return __builtin_bit_cast(float, u & 0xFFFF0000u); }
__device__ inline float relu6f(float x) { return fminf(fmaxf(x, 0.f), 6.f); }

// ---------------- K1: x1 = relu6(bn1(feats @ W1)) as bf16, pure VALU GEMM ----------------
// 32 rows/block, 192 threads: thread = (colgroup of 8 ch) x (slot of 4 rows).
// feats staged transposed+padded in LDS (conflict-free); stores are uint4 (16 B/lane).
__global__ __launch_bounds__(192) void k1_expand(
    const float* __restrict__ feats, const float* __restrict__ W1,
    const float* __restrict__ g1, const float* __restrict__ b1,
    const float* __restrict__ m1, const float* __restrict__ v1,
    unsigned short* __restrict__ x1, int N)
{
    __shared__ float fL[32 * 33];                // fL[ch*33 + row], +1 pad
    const int tid = threadIdx.x;
    const int rowbase = blockIdx.x * 32;

    // cooperative transposed stage of feats[rowbase..rowbase+31][0..31]
    for (int i = tid; i < 1024; i += 192) {
        int r = i >> 5, c = i & 31;
        int gr = rowbase + r;
        float v = (gr < N) ? feats[(size_t)gr * 32 + c] : 0.f;  // coalesced: addr = rowbase*32 + i
        fL[c * 33 + r] = v;                                     // bank = (c + r) % 32: conflict-free
    }

    const int cg = tid % 24;      // 24 col-groups x 8 ch = 192 channels
    const int slot = tid / 24;    // 8 slots x 4 rows = 32 rows
    const int c0 = cg * 8;

    float s[8], bb[8];
#pragma unroll
    for (int j = 0; j < 8; ++j) {
        int c = c0 + j;
        s[j] = g1[c] * rsqrtf(v1[c] + EPS);
        bb[j] = b1[c] - m1[c] * s[j];
    }

    __syncthreads();

    float acc[4][8];
#pragma unroll
    for (int r = 0; r < 4; ++r)
#pragma unroll
        for (int j = 0; j < 8; ++j) acc[r][j] = 0.f;

    for (int k = 0; k < 32; ++k) {
        float4 wa = *(const float4*)(W1 + k * 192 + c0);
        float4 wb = *(const float4*)(W1 + k * 192 + c0 + 4);
        float w[8] = {wa.x, wa.y, wa.z, wa.w, wb.x, wb.y, wb.z, wb.w};
#pragma unroll
        for (int r = 0; r < 4; ++r) {
            float f = fL[k * 33 + slot + 8 * r];   // broadcast within col-groups, banks differ by slot
#pragma unroll
            for (int j = 0; j < 8; ++j) acc[r][j] = fmaf(f, w[j], acc[r][j]);
        }
    }

#pragma unroll
    for (int r = 0; r < 4; ++r) {
        int row = rowbase + slot + 8 * r;
        if (row < N) {
            unsigned pk[4];
#pragma unroll
            for (int d = 0; d < 4; ++d) {
                float lo = relu6f(fmaf(acc[r][2 * d],     s[2 * d],     bb[2 * d]));
                float hi = relu6f(fmaf(acc[r][2 * d + 1], s[2 * d + 1], bb[2 * d + 1]));
                pk[d] = (unsigned)f32_to_bf16(lo) | ((unsigned)f32_to_bf16(hi) << 16);
            }
            uint4 q = {pk[0], pk[1], pk[2], pk[3]};
            *(uint4*)(x1 + (size_t)row * 192 + c0) = q;   // 16B aligned: 384*row + 16*cg
        }
    }
}

// ------- K2: fused depthwise gather + bn2 + relu6 + project GEMM + bn3 + residual -------
// Phase A: 48 col-groups x 4 ch, 4 row-slots; nbr tile staged in LDS; branchless 8B gathers,
// all 9 in flight per row, 12 row-iterations fully unrolled for cross-iter MLP.
__global__ __launch_bounds__(192) void k2_fused(
    const unsigned short* __restrict__ x1, const int* __restrict__ nbr,
    const float* __restrict__ W2, const float* __restrict__ W3,
    const float* __restrict__ g2, const float* __restrict__ b2,
    const float* __restrict__ m2, const float* __restrict__ v2,
    const float* __restrict__ g3, const float* __restrict__ b3,
    const float* __restrict__ m3, const float* __restrict__ v3,
    const float* __restrict__ feats, float* __restrict__ out, int N)
{
    __shared__ __align__(16) unsigned short x2L[48 * 200];   // stride 200: phase-B b128 conflict-free
    __shared__ __align__(16) int nbrL[48 * 12];              // stride 12: b128-aligned rows
    const int tid = threadIdx.x;
    const int rowbase = blockIdx.x * 48;

    // stage nbr tile (coalesced read: nbr[rowbase*9 + i])
    for (int i = tid; i < 432; i += 192) {
        int r = i / 9, k = i - r * 9;
        int n = rowbase + r;
        nbrL[r * 12 + k] = (n < N) ? nbr[(size_t)n * 9 + k] : -1;
    }

    const int cg = tid % 48;     // 48 col-groups x 4 ch
    const int slot = tid / 48;   // 4 row-slots
    const int c0 = cg * 4;

    float w2[9][4];
#pragma unroll
    for (int k = 0; k < 9; ++k) {
        float4 w = *(const float4*)(W2 + k * 192 + c0);
        w2[k][0] = w.x; w2[k][1] = w.y; w2[k][2] = w.z; w2[k][3] = w.w;
    }
    float s2[4], bb2[4];
#pragma unroll
    for (int j = 0; j < 4; ++j) {
        int c = c0 + j;
        s2[j] = g2[c] * rsqrtf(v2[c] + EPS);
        bb2[j] = b2[c] - m2[c] * s2[j];
    }
    __syncthreads();

#pragma unroll
    for (int it = 0; it < 12; ++it) {
        int r = it * 4 + slot;
        const int* nb = &nbrL[r * 12];
        int4 n03 = *(const int4*)nb;
        int4 n47 = *(const int4*)(nb + 4);
        int n8 = nb[8];
        int idx[9] = {n03.x, n03.y, n03.z, n03.w, n47.x, n47.y, n47.z, n47.w, n8};
        uint2 gv[9];
#pragma unroll
        for (int k = 0; k < 9; ++k) {
            int safe = idx[k] < 0 ? 0 : idx[k];              // branchless: clamp addr...
            gv[k] = *(const uint2*)(x1 + (size_t)safe * 192 + c0);
        }
        float a0 = 0.f, a1 = 0.f, a2 = 0.f, a3 = 0.f;
#pragma unroll
        for (int k = 0; k < 9; ++k) {
            unsigned ux = idx[k] >= 0 ? gv[k].x : 0u;        // ...and select result
            unsigned uy = idx[k] >= 0 ? gv[k].y : 0u;
            a0 = fmaf(bf16_lo(ux), w2[k][0], a0);
            a1 = fmaf(bf16_hi(ux), w2[k][1], a1);
            a2 = fmaf(bf16_lo(uy), w2[k][2], a2);
            a3 = fmaf(bf16_hi(uy), w2[k][3], a3);
        }
        a0 = relu6f(fmaf(a0, s2[0], bb2[0]));
        a1 = relu6f(fmaf(a1, s2[1], bb2[1]));
        a2 = relu6f(fmaf(a2, s2[2], bb2[2]));
        a3 = relu6f(fmaf(a3, s2[3], bb2[3]));
        uint2 pk;
        pk.x = (unsigned)f32_to_bf16(a0) | ((unsigned)f32_to_bf16(a1) << 16);
        pk.y = (unsigned)f32_to_bf16(a2) | ((unsigned)f32_to_bf16(a3) << 16);
        *(uint2*)(&x2L[r * 200 + c0]) = pk;                  // 8B aligned: 400r + 8cg
    }
    __syncthreads();

    // ---- phase B: [48x192] @ [192x32] via MFMA, wave w -> rows 16w..16w+15 ----
    const int lane = tid & 63;
    const int wave = tid >> 6;
    const int m = lane & 15;
    const int q = lane >> 4;

    bf16x8 bfrag[12];                            // W3 B-frags: k = 32s+q*8+j, n = 16t+m
#pragma unroll
    for (int s = 0; s < 6; ++s)
#pragma unroll
        for (int t = 0; t < 2; ++t) {
            BF8 tmp;
#pragma unroll
            for (int j = 0; j < 8; ++j)
                tmp.u[j] = f32_to_bf16(W3[(32 * s + q * 8 + j) * 32 + 16 * t + m]);
            bfrag[s * 2 + t] = tmp.v;
        }

    f32x4 acc0 = {0.f, 0.f, 0.f, 0.f}, acc1 = {0.f, 0.f, 0.f, 0.f};
    const int rw = wave * 16;
#pragma unroll
    for (int s = 0; s < 6; ++s) {
        bf16x8 a = *reinterpret_cast<const bf16x8*>(&x2L[(rw + m) * 200 + 32 * s + q * 8]);
        acc0 = __builtin_amdgcn_mfma_f32_16x16x32_bf16(a, bfrag[s * 2 + 0], acc0, 0, 0, 0);
        acc1 = __builtin_amdgcn_mfma_f32_16x16x32_bf16(a, bfrag[s * 2 + 1], acc1, 0, 0, 0);
    }

#pragma unroll
    for (int t = 0; t < 2; ++t) {
        f32x4 acc = (t == 0) ? acc0 : acc1;
        int c = 16 * t + m;
        float s3  = g3[c] * rsqrtf(v3[c] + EPS);
        float bb3 = b3[c] - m3[c] * s3;
#pragma unroll
        for (int i = 0; i < 4; ++i) {
            int r = rowbase + rw + q * 4 + i;
            if (r < N) {
                int o = r * 32 + c;
                out[o] = fmaf(acc[i], s3, bb3) + feats[o];
            }
        }
    }
}

extern "C" void kernel_launch(void* const* d_in, const int* in_sizes, int n_in,
                              void* d_out, int out_size, void* d_ws, size_t ws_size,
                              hipStream_t stream) {
    const float* feats = (const float*)d_in[0];
    const int*   nbr   = (const int*)d_in[1];
    const float* W1    = (const float*)d_in[2];
    const float* W2    = (const float*)d_in[3];
    const float* W3    = (const float*)d_in[4];
    const float* g1 = (const float*)d_in[5];
    const float* b1 = (const float*)d_in[6];
    const float* m1 = (const float*)d_in[7];
    const float* v1 = (const float*)d_in[8];
    const float* g2 = (const float*)d_in[9];
    const float* b2 = (const float*)d_in[10];
    const float* m2 = (const float*)d_in[11];
    const float* v2 = (const float*)d_in[12];
    const float* g3 = (const float*)d_in[13];
    const float* b3 = (const float*)d_in[14];
    const float* m3 = (const float*)d_in[15];
    const float* v3 = (const float*)d_in[16];
    float* out = (float*)d_out;

    const int N = in_sizes[0] / 32;
    unsigned short* x1 = (unsigned short*)d_ws;   // N*192 bf16 = 76.8 MB

    k1_expand<<<dim3((N + 31) / 32), dim3(192), 0, stream>>>(
        feats, W1, g1, b1, m1, v1, x1, N);
    k2_fused<<<dim3((N + 47) / 48), dim3(192), 0, stream>>>(
        x1, nbr, W2, W3, g2, b2, m2, v2, g3, b3, m3, v3, feats, out, N);
}

// Round 3
// 237.100 us; speedup vs baseline: 2.0905x; 1.5414x over previous
//
#include <hip/hip_runtime.h>

#define EPS 1e-5f

typedef __bf16 bf16x8 __attribute__((ext_vector_type(8)));
typedef float f32x4 __attribute__((ext_vector_type(4)));

union BF8 { bf16x8 v; unsigned short u[8]; uint4 q; };

__device__ inline unsigned short f32_to_bf16(float f) {
    unsigned u = __builtin_bit_cast(unsigned, f);
    return (unsigned short)((u + 0x7FFFu + ((u >> 16) & 1u)) >> 16);
}
__device__ inline float bf16_lo(unsigned u) { return __builtin_bit_cast(float, u << 16); }
__device__ inline float bf16_hi(unsigned u) { return __builtin_bit_cast(float, u & 0xFFFF0000u); }
__device__ inline float relu6f(float x) { return fminf(fmaxf(x, 0.f), 6.f); }

// ---------------- K1: x1 = relu6(bn1(feats @ W1)) as bf16, MFMA ----------------
// 256 threads (4 waves), 64 rows/block. W1 staged transposed in LDS (b128 B-frags),
// feats staged as bf16 A-tile, epilogue repacked through LDS for contiguous uint4 stores.
__global__ __launch_bounds__(256) void k1_expand(
    const float* __restrict__ feats, const float* __restrict__ W1,
    const float* __restrict__ g1, const float* __restrict__ b1,
    const float* __restrict__ m1, const float* __restrict__ v1,
    unsigned short* __restrict__ x1, int N)
{
    __shared__ __align__(16) unsigned short w1t[192 * 40];  // W1T[n][k], stride 40
    __shared__ __align__(16) unsigned short aT[64 * 40];    // A[r][k] bf16, stride 40
    __shared__ __align__(16) unsigned short outT[64 * 200]; // out[r][c] bf16, stride 200
    __shared__ float sL[192], bL[192];
    const int tid = threadIdx.x;
    const int rowbase = blockIdx.x * 64;

    // per-channel bn constants (once per block)
    if (tid < 192) {
        float s = g1[tid] * rsqrtf(v1[tid] + EPS);
        sL[tid] = s;
        bL[tid] = b1[tid] - m1[tid] * s;
    }

    // stage W1 transposed -> bf16 (coalesced float4 reads; scattered u16 LDS writes, one-time)
#pragma unroll
    for (int j = 0; j < 6; ++j) {
        int f = (j * 256 + tid) * 4;           // 6144 elements, 192%4==0 so k uniform per float4
        float4 w = *(const float4*)(W1 + f);
        int k = f / 192, n = f % 192;
        w1t[(n + 0) * 40 + k] = f32_to_bf16(w.x);
        w1t[(n + 1) * 40 + k] = f32_to_bf16(w.y);
        w1t[(n + 2) * 40 + k] = f32_to_bf16(w.z);
        w1t[(n + 3) * 40 + k] = f32_to_bf16(w.w);
    }

    // stage feats tile -> bf16 A (thread: row tid/4, cols 8*(tid&3)..+7)
    {
        int r = tid >> 2, c = (tid & 3) * 8;
        int gr = rowbase + r;
        float4 f0 = {0.f,0.f,0.f,0.f}, f1 = {0.f,0.f,0.f,0.f};
        if (gr < N) {
            f0 = *(const float4*)(feats + (size_t)gr * 32 + c);
            f1 = *(const float4*)(feats + (size_t)gr * 32 + c + 4);
        }
        BF8 p;
        p.u[0] = f32_to_bf16(f0.x); p.u[1] = f32_to_bf16(f0.y);
        p.u[2] = f32_to_bf16(f0.z); p.u[3] = f32_to_bf16(f0.w);
        p.u[4] = f32_to_bf16(f1.x); p.u[5] = f32_to_bf16(f1.y);
        p.u[6] = f32_to_bf16(f1.z); p.u[7] = f32_to_bf16(f1.w);
        *(uint4*)(&aT[r * 40 + c]) = p.q;      // 80r+2c: 16B aligned
    }
    __syncthreads();

    const int lane = tid & 63, wave = tid >> 6;
    const int m = lane & 15, q = lane >> 4;

    // A-frag: row 16*wave+m, k = q*8..q*8+7 (b128, 2-way bank alias: free)
    bf16x8 af = *(const bf16x8*)(&aT[(wave * 16 + m) * 40 + q * 8]);

    f32x4 acc[12];
#pragma unroll
    for (int t = 0; t < 12; ++t) {
        bf16x8 bf = *(const bf16x8*)(&w1t[(16 * t + m) * 40 + q * 8]);
        f32x4 z = {0.f, 0.f, 0.f, 0.f};
        acc[t] = __builtin_amdgcn_mfma_f32_16x16x32_bf16(af, bf, z, 0, 0, 0);
    }

    // epilogue: bn + relu6 -> bf16 -> outT (C layout: col=16t+m, row=16*wave+q*4+i)
#pragma unroll
    for (int t = 0; t < 12; ++t) {
        int c = 16 * t + m;
        float s = sL[c], bb = bL[c];
#pragma unroll
        for (int i = 0; i < 4; ++i) {
            int r = wave * 16 + q * 4 + i;
            outT[r * 200 + c] = f32_to_bf16(relu6f(fmaf(acc[t][i], s, bb)));
        }
    }
    __syncthreads();

    // readout: contiguous uint4 stores (wave covers 1KB contiguous global)
#pragma unroll
    for (int j = 0; j < 6; ++j) {
        int i = j * 256 + tid;                 // 64 rows x 24 uint4-chunks
        int r = i / 24, c = i % 24;
        int gr = rowbase + r;
        if (gr < N)
            *(uint4*)(x1 + (size_t)gr * 192 + c * 8) = *(const uint4*)(&outT[r * 200 + c * 8]);
    }
}

// ------- K2: fused depthwise gather + bn2 + relu6 + project GEMM + bn3 + residual -------
// (unchanged from R1 — improved 372 -> ~165 us there; isolate k1 rewrite this round)
__global__ __launch_bounds__(192) void k2_fused(
    const unsigned short* __restrict__ x1, const int* __restrict__ nbr,
    const float* __restrict__ W2, const float* __restrict__ W3,
    const float* __restrict__ g2, const float* __restrict__ b2,
    const float* __restrict__ m2, const float* __restrict__ v2,
    const float* __restrict__ g3, const float* __restrict__ b3,
    const float* __restrict__ m3, const float* __restrict__ v3,
    const float* __restrict__ feats, float* __restrict__ out, int N)
{
    __shared__ __align__(16) unsigned short x2L[48 * 200];
    __shared__ __align__(16) int nbrL[48 * 12];
    const int tid = threadIdx.x;
    const int rowbase = blockIdx.x * 48;

    for (int i = tid; i < 432; i += 192) {
        int r = i / 9, k = i - r * 9;
        int n = rowbase + r;
        nbrL[r * 12 + k] = (n < N) ? nbr[(size_t)n * 9 + k] : -1;
    }

    const int cg = tid % 48;
    const int slot = tid / 48;
    const int c0 = cg * 4;

    float w2[9][4];
#pragma unroll
    for (int k = 0; k < 9; ++k) {
        float4 w = *(const float4*)(W2 + k * 192 + c0);
        w2[k][0] = w.x; w2[k][1] = w.y; w2[k][2] = w.z; w2[k][3] = w.w;
    }
    float s2[4], bb2[4];
#pragma unroll
    for (int j = 0; j < 4; ++j) {
        int c = c0 + j;
        s2[j] = g2[c] * rsqrtf(v2[c] + EPS);
        bb2[j] = b2[c] - m2[c] * s2[j];
    }
    __syncthreads();

#pragma unroll
    for (int it = 0; it < 12; ++it) {
        int r = it * 4 + slot;
        const int* nb = &nbrL[r * 12];
        int4 n03 = *(const int4*)nb;
        int4 n47 = *(const int4*)(nb + 4);
        int n8 = nb[8];
        int idx[9] = {n03.x, n03.y, n03.z, n03.w, n47.x, n47.y, n47.z, n47.w, n8};
        uint2 gv[9];
#pragma unroll
        for (int k = 0; k < 9; ++k) {
            int safe = idx[k] < 0 ? 0 : idx[k];
            gv[k] = *(const uint2*)(x1 + (size_t)safe * 192 + c0);
        }
        float a0 = 0.f, a1 = 0.f, a2 = 0.f, a3 = 0.f;
#pragma unroll
        for (int k = 0; k < 9; ++k) {
            unsigned ux = idx[k] >= 0 ? gv[k].x : 0u;
            unsigned uy = idx[k] >= 0 ? gv[k].y : 0u;
            a0 = fmaf(bf16_lo(ux), w2[k][0], a0);
            a1 = fmaf(bf16_hi(ux), w2[k][1], a1);
            a2 = fmaf(bf16_lo(uy), w2[k][2], a2);
            a3 = fmaf(bf16_hi(uy), w2[k][3], a3);
        }
        a0 = relu6f(fmaf(a0, s2[0], bb2[0]));
        a1 = relu6f(fmaf(a1, s2[1], bb2[1]));
        a2 = relu6f(fmaf(a2, s2[2], bb2[2]));
        a3 = relu6f(fmaf(a3, s2[3], bb2[3]));
        uint2 pk;
        pk.x = (unsigned)f32_to_bf16(a0) | ((unsigned)f32_to_bf16(a1) << 16);
        pk.y = (unsigned)f32_to_bf16(a2) | ((unsigned)f32_to_bf16(a3) << 16);
        *(uint2*)(&x2L[r * 200 + c0]) = pk;
    }
    __syncthreads();

    const int lane = tid & 63;
    const int wave = tid >> 6;
    const int m = lane & 15;
    const int q = lane >> 4;

    bf16x8 bfrag[12];
#pragma unroll
    for (int s = 0; s < 6; ++s)
#pragma unroll
        for (int t = 0; t < 2; ++t) {
            BF8 tmp;
#pragma unroll
            for (int j = 0; j < 8; ++j)
                tmp.u[j] = f32_to_bf16(W3[(32 * s + q * 8 + j) * 32 + 16 * t + m]);
            bfrag[s * 2 + t] = tmp.v;
        }

    f32x4 acc0 = {0.f, 0.f, 0.f, 0.f}, acc1 = {0.f, 0.f, 0.f, 0.f};
    const int rw = wave * 16;
#pragma unroll
    for (int s = 0; s < 6; ++s) {
        bf16x8 a = *reinterpret_cast<const bf16x8*>(&x2L[(rw + m) * 200 + 32 * s + q * 8]);
        acc0 = __builtin_amdgcn_mfma_f32_16x16x32_bf16(a, bfrag[s * 2 + 0], acc0, 0, 0, 0);
        acc1 = __builtin_amdgcn_mfma_f32_16x16x32_bf16(a, bfrag[s * 2 + 1], acc1, 0, 0, 0);
    }

#pragma unroll
    for (int t = 0; t < 2; ++t) {
        f32x4 acc = (t == 0) ? acc0 : acc1;
        int c = 16 * t + m;
        float s3  = g3[c] * rsqrtf(v3[c] + EPS);
        float bb3 = b3[c] - m3[c] * s3;
#pragma unroll
        for (int i = 0; i < 4; ++i) {
            int r = rowbase + rw + q * 4 + i;
            if (r < N) {
                int o = r * 32 + c;
                out[o] = fmaf(acc[i], s3, bb3) + feats[o];
            }
        }
    }
}

extern "C" void kernel_launch(void* const* d_in, const int* in_sizes, int n_in,
                              void* d_out, int out_size, void* d_ws, size_t ws_size,
                              hipStream_t stream) {
    const float* feats = (const float*)d_in[0];
    const int*   nbr   = (const int*)d_in[1];
    const float* W1    = (const float*)d_in[2];
    const float* W2    = (const float*)d_in[3];
    const float* W3    = (const float*)d_in[4];
    const float* g1 = (const float*)d_in[5];
    const float* b1 = (const float*)d_in[6];
    const float* m1 = (const float*)d_in[7];
    const float* v1 = (const float*)d_in[8];
    const float* g2 = (const float*)d_in[9];
    const float* b2 = (const float*)d_in[10];
    const float* m2 = (const float*)d_in[11];
    const float* v2 = (const float*)d_in[12];
    const float* g3 = (const float*)d_in[13];
    const float* b3 = (const float*)d_in[14];
    const float* m3 = (const float*)d_in[15];
    const float* v3 = (const float*)d_in[16];
    float* out = (float*)d_out;

    const int N = in_sizes[0] / 32;
    unsigned short* x1 = (unsigned short*)d_ws;   // N*192 bf16 = 76.8 MB

    k1_expand<<<dim3((N + 63) / 64), dim3(256), 0, stream>>>(
        feats, W1, g1, b1, m1, v1, x1, N);
    k2_fused<<<dim3((N + 47) / 48), dim3(192), 0, stream>>>(
        x1, nbr, W2, W3, g2, b2, m2, v2, g3, b3, m3, v3, feats, out, N);
}

// Round 4
// 229.557 us; speedup vs baseline: 2.1592x; 1.0329x over previous
//
#include <hip/hip_runtime.h>

#define EPS 1e-5f

typedef __bf16 bf16x8 __attribute__((ext_vector_type(8)));
typedef float f32x4 __attribute__((ext_vector_type(4)));

union BF8 { bf16x8 v; unsigned short u[8]; uint4 q; };

__device__ inline unsigned short f32_to_bf16(float f) {
    unsigned u = __builtin_bit_cast(unsigned, f);
    return (unsigned short)((u + 0x7FFFu + ((u >> 16) & 1u)) >> 16);
}
__device__ inline float bf16_lo(unsigned u) { return __builtin_bit_cast(float, u << 16); }
__device__ inline float bf16_hi(unsigned u) { return __builtin_bit_cast(float, u & 0xFFFF0000u); }
__device__ inline float relu6f(float x) { return fminf(fmaxf(x, 0.f), 6.f); }

// ---- K0: one-time prep. w1t = W1^T bf16 [192][32]; w3t = W3^T bf16 [32][192];
//      bnc = {s1[192], b1'[192], s2[192], b2'[192], s3[32], b3'[32]}  (832 floats)
__global__ __launch_bounds__(256) void k0_prep(
    const float* __restrict__ W1, const float* __restrict__ W3,
    const float* __restrict__ g1, const float* __restrict__ b1,
    const float* __restrict__ m1, const float* __restrict__ v1,
    const float* __restrict__ g2, const float* __restrict__ b2,
    const float* __restrict__ m2, const float* __restrict__ v2,
    const float* __restrict__ g3, const float* __restrict__ b3,
    const float* __restrict__ m3, const float* __restrict__ v3,
    unsigned short* __restrict__ w1t, unsigned short* __restrict__ w3t,
    float* __restrict__ bnc)
{
    const int gtid = blockIdx.x * 256 + threadIdx.x;
    const int gstr = gridDim.x * 256;
    for (int i = gtid; i < 6144; i += gstr) {          // w1t[n*32+k] = W1[k*192+n]
        int n = i >> 5, k = i & 31;
        w1t[i] = f32_to_bf16(W1[k * 192 + n]);
    }
    for (int i = gtid; i < 6144; i += gstr) {          // w3t[n*192+k] = W3[k*32+n]
        int n = i / 192, k = i - n * 192;
        w3t[i] = f32_to_bf16(W3[k * 32 + n]);
    }
    if (blockIdx.x == 0) {
        int t = threadIdx.x;
        if (t < 192) {
            float s = g1[t] * rsqrtf(v1[t] + EPS);
            bnc[t] = s; bnc[192 + t] = b1[t] - m1[t] * s;
            float u = g2[t] * rsqrtf(v2[t] + EPS);
            bnc[384 + t] = u; bnc[576 + t] = b2[t] - m2[t] * u;
            if (t < 32) {
                float w = g3[t] * rsqrtf(v3[t] + EPS);
                bnc[768 + t] = w; bnc[800 + t] = b3[t] - m3[t] * w;
            }
        }
    }
}

// ---------------- K1: x1 = relu6(bn1(feats @ W1)) as bf16, MFMA ----------------
// 256 threads, 64 rows/block. B-frags: 12 b128 loads from L2-hot w1t (no LDS staging).
__global__ __launch_bounds__(256) void k1_expand(
    const float* __restrict__ feats, const unsigned short* __restrict__ w1t,
    const float* __restrict__ bnc, unsigned short* __restrict__ x1, int N)
{
    __shared__ __align__(16) unsigned short aT[64 * 40];    // A[r][k] bf16, stride 40
    __shared__ __align__(16) unsigned short outT[64 * 200]; // out[r][c] bf16, stride 200
    const int tid = threadIdx.x;
    const int rowbase = blockIdx.x * 64;

    // stage feats tile -> bf16 A (thread: row tid/4, cols 8*(tid&3)..+7)
    {
        int r = tid >> 2, c = (tid & 3) * 8;
        int gr = rowbase + r;
        float4 f0 = {0.f,0.f,0.f,0.f}, f1 = {0.f,0.f,0.f,0.f};
        if (gr < N) {
            f0 = *(const float4*)(feats + (size_t)gr * 32 + c);
            f1 = *(const float4*)(feats + (size_t)gr * 32 + c + 4);
        }
        BF8 p;
        p.u[0] = f32_to_bf16(f0.x); p.u[1] = f32_to_bf16(f0.y);
        p.u[2] = f32_to_bf16(f0.z); p.u[3] = f32_to_bf16(f0.w);
        p.u[4] = f32_to_bf16(f1.x); p.u[5] = f32_to_bf16(f1.y);
        p.u[6] = f32_to_bf16(f1.z); p.u[7] = f32_to_bf16(f1.w);
        *(uint4*)(&aT[r * 40 + c]) = p.q;
    }
    __syncthreads();

    const int lane = tid & 63, wave = tid >> 6;
    const int m = lane & 15, q = lane >> 4;

    bf16x8 af = *(const bf16x8*)(&aT[(wave * 16 + m) * 40 + q * 8]);

    f32x4 acc[12];
#pragma unroll
    for (int t = 0; t < 12; ++t) {
        bf16x8 bf = *(const bf16x8*)(w1t + (16 * t + m) * 32 + q * 8);  // b128, L2-hot
        f32x4 z = {0.f, 0.f, 0.f, 0.f};
        acc[t] = __builtin_amdgcn_mfma_f32_16x16x32_bf16(af, bf, z, 0, 0, 0);
    }

#pragma unroll
    for (int t = 0; t < 12; ++t) {
        int c = 16 * t + m;
        float s = bnc[c], bb = bnc[192 + c];
#pragma unroll
        for (int i = 0; i < 4; ++i) {
            int r = wave * 16 + q * 4 + i;
            outT[r * 200 + c] = f32_to_bf16(relu6f(fmaf(acc[t][i], s, bb)));
        }
    }
    __syncthreads();

    // readout: contiguous uint4 stores
#pragma unroll
    for (int j = 0; j < 6; ++j) {
        int i = j * 256 + tid;
        int r = i / 24, c = i % 24;
        int gr = rowbase + r;
        if (gr < N)
            *(uint4*)(x1 + (size_t)gr * 192 + c * 8) = *(const uint4*)(&outT[r * 200 + c * 8]);
    }
}

// ------- K2: fused depthwise gather + bn2 + relu6 + project GEMM + bn3 + residual -------
// Phase A: 48 col-groups x 4 ch; 2 rows per iteration -> 18 gathers in flight; neighbor
// offsets staged PRE-MULTIPLIED to byte offsets. Phase B frags from L2-hot w3t (b128).
__global__ __launch_bounds__(192) void k2_fused(
    const unsigned short* __restrict__ x1, const int* __restrict__ nbr,
    const float* __restrict__ W2, const unsigned short* __restrict__ w3t,
    const float* __restrict__ bnc, const float* __restrict__ feats,
    float* __restrict__ out, int N)
{
    __shared__ __align__(16) unsigned short x2L[48 * 200];
    __shared__ __align__(16) int offL[48 * 12];     // byte offsets into x1; -1 = invalid
    const int tid = threadIdx.x;
    const int rowbase = blockIdx.x * 48;

    for (int i = tid; i < 432; i += 192) {
        int r = i / 9, k = i - r * 9;
        int n = rowbase + r;
        int idx = (n < N) ? nbr[(size_t)n * 9 + k] : -1;
        offL[r * 12 + k] = (idx < 0) ? -1 : idx * 384;   // 384 B per x1 row
    }

    const int cg = tid % 48;
    const int slot = tid / 48;
    const int c0 = cg * 4;
    const char* x1b = (const char*)x1 + c0 * 2;          // fold channel offset

    float w2v[9][4];
#pragma unroll
    for (int k = 0; k < 9; ++k) {
        float4 w = *(const float4*)(W2 + k * 192 + c0);
        w2v[k][0] = w.x; w2v[k][1] = w.y; w2v[k][2] = w.z; w2v[k][3] = w.w;
    }
    float4 s2 = *(const float4*)(bnc + 384 + c0);
    float4 bb2 = *(const float4*)(bnc + 576 + c0);
    __syncthreads();

#pragma unroll
    for (int it = 0; it < 6; ++it) {
        int r0 = it * 8 + slot, r1 = r0 + 4;
        const int* nA = &offL[r0 * 12];
        const int* nB = &offL[r1 * 12];
        int4 a03 = *(const int4*)nA; int4 a47 = *(const int4*)(nA + 4); int a8 = nA[8];
        int4 b03 = *(const int4*)nB; int4 b47 = *(const int4*)(nB + 4); int b8 = nB[8];
        int offA[9] = {a03.x, a03.y, a03.z, a03.w, a47.x, a47.y, a47.z, a47.w, a8};
        int offB[9] = {b03.x, b03.y, b03.z, b03.w, b47.x, b47.y, b47.z, b47.w, b8};
        uint2 gA[9], gB[9];
#pragma unroll
        for (int k = 0; k < 9; ++k) {
            gA[k] = *(const uint2*)(x1b + (offA[k] < 0 ? 0 : offA[k]));
            gB[k] = *(const uint2*)(x1b + (offB[k] < 0 ? 0 : offB[k]));
        }
        float a0 = 0.f, a1 = 0.f, a2 = 0.f, a3 = 0.f;
        float c0f = 0.f, c1 = 0.f, c2 = 0.f, c3 = 0.f;
#pragma unroll
        for (int k = 0; k < 9; ++k) {
            unsigned ax = offA[k] >= 0 ? gA[k].x : 0u;
            unsigned ay = offA[k] >= 0 ? gA[k].y : 0u;
            a0 = fmaf(bf16_lo(ax), w2v[k][0], a0);
            a1 = fmaf(bf16_hi(ax), w2v[k][1], a1);
            a2 = fmaf(bf16_lo(ay), w2v[k][2], a2);
            a3 = fmaf(bf16_hi(ay), w2v[k][3], a3);
            unsigned bx = offB[k] >= 0 ? gB[k].x : 0u;
            unsigned by = offB[k] >= 0 ? gB[k].y : 0u;
            c0f = fmaf(bf16_lo(bx), w2v[k][0], c0f);
            c1  = fmaf(bf16_hi(bx), w2v[k][1], c1);
            c2  = fmaf(bf16_lo(by), w2v[k][2], c2);
            c3  = fmaf(bf16_hi(by), w2v[k][3], c3);
        }
        a0 = relu6f(fmaf(a0, s2.x, bb2.x));
        a1 = relu6f(fmaf(a1, s2.y, bb2.y));
        a2 = relu6f(fmaf(a2, s2.z, bb2.z));
        a3 = relu6f(fmaf(a3, s2.w, bb2.w));
        c0f = relu6f(fmaf(c0f, s2.x, bb2.x));
        c1  = relu6f(fmaf(c1,  s2.y, bb2.y));
        c2  = relu6f(fmaf(c2,  s2.z, bb2.z));
        c3  = relu6f(fmaf(c3,  s2.w, bb2.w));
        uint2 pA, pB;
        pA.x = (unsigned)f32_to_bf16(a0) | ((unsigned)f32_to_bf16(a1) << 16);
        pA.y = (unsigned)f32_to_bf16(a2) | ((unsigned)f32_to_bf16(a3) << 16);
        pB.x = (unsigned)f32_to_bf16(c0f) | ((unsigned)f32_to_bf16(c1) << 16);
        pB.y = (unsigned)f32_to_bf16(c2)  | ((unsigned)f32_to_bf16(c3) << 16);
        *(uint2*)(&x2L[r0 * 200 + c0]) = pA;
        *(uint2*)(&x2L[r1 * 200 + c0]) = pB;
    }
    __syncthreads();

    // ---- phase B: [48x192] @ [192x32] via MFMA ----
    const int lane = tid & 63;
    const int wave = tid >> 6;
    const int m = lane & 15;
    const int q = lane >> 4;

    bf16x8 bfrag[12];
#pragma unroll
    for (int s = 0; s < 6; ++s)
#pragma unroll
        for (int t = 0; t < 2; ++t)
            bfrag[s * 2 + t] = *(const bf16x8*)(w3t + (16 * t + m) * 192 + 32 * s + q * 8);

    f32x4 acc0 = {0.f, 0.f, 0.f, 0.f}, acc1 = {0.f, 0.f, 0.f, 0.f};
    const int rw = wave * 16;
#pragma unroll
    for (int s = 0; s < 6; ++s) {
        bf16x8 a = *reinterpret_cast<const bf16x8*>(&x2L[(rw + m) * 200 + 32 * s + q * 8]);
        acc0 = __builtin_amdgcn_mfma_f32_16x16x32_bf16(a, bfrag[s * 2 + 0], acc0, 0, 0, 0);
        acc1 = __builtin_amdgcn_mfma_f32_16x16x32_bf16(a, bfrag[s * 2 + 1], acc1, 0, 0, 0);
    }

#pragma unroll
    for (int t = 0; t < 2; ++t) {
        f32x4 acc = (t == 0) ? acc0 : acc1;
        int c = 16 * t + m;
        float s3 = bnc[768 + c], bb3 = bnc[800 + c];
#pragma unroll
        for (int i = 0; i < 4; ++i) {
            int r = rowbase + rw + q * 4 + i;
            if (r < N) {
                int o = r * 32 + c;
                out[o] = fmaf(acc[i], s3, bb3) + feats[o];
            }
        }
    }
}

extern "C" void kernel_launch(void* const* d_in, const int* in_sizes, int n_in,
                              void* d_out, int out_size, void* d_ws, size_t ws_size,
                              hipStream_t stream) {
    const float* feats = (const float*)d_in[0];
    const int*   nbr   = (const int*)d_in[1];
    const float* W1    = (const float*)d_in[2];
    const float* W2    = (const float*)d_in[3];
    const float* W3    = (const float*)d_in[4];
    const float* g1 = (const float*)d_in[5];
    const float* b1 = (const float*)d_in[6];
    const float* m1 = (const float*)d_in[7];
    const float* v1 = (const float*)d_in[8];
    const float* g2 = (const float*)d_in[9];
    const float* b2 = (const float*)d_in[10];
    const float* m2 = (const float*)d_in[11];
    const float* v2 = (const float*)d_in[12];
    const float* g3 = (const float*)d_in[13];
    const float* b3 = (const float*)d_in[14];
    const float* m3 = (const float*)d_in[15];
    const float* v3 = (const float*)d_in[16];
    float* out = (float*)d_out;

    const int N = in_sizes[0] / 32;

    // ws layout: x1 [N*192 bf16 = 76.8 MB] | w1t [12,288 B] | w3t [12,288 B] | bnc [3,328 B]
    char* ws = (char*)d_ws;
    unsigned short* x1  = (unsigned short*)ws;
    unsigned short* w1t = (unsigned short*)(ws + (size_t)N * 192 * 2);
    unsigned short* w3t = w1t + 6144;
    float*          bnc = (float*)(w3t + 6144);

    k0_prep<<<dim3(32), dim3(256), 0, stream>>>(
        W1, W3, g1, b1, m1, v1, g2, b2, m2, v2, g3, b3, m3, v3, w1t, w3t, bnc);
    k1_expand<<<dim3((N + 63) / 64), dim3(256), 0, stream>>>(
        feats, w1t, bnc, x1, N);
    k2_fused<<<dim3((N + 47) / 48), dim3(192), 0, stream>>>(
        x1, nbr, W2, w3t, bnc, feats, out, N);
}

// Round 5
// 197.315 us; speedup vs baseline: 2.5121x; 1.1634x over previous
//
#include <hip/hip_runtime.h>

#define EPS 1e-5f

typedef __bf16 bf16x8 __attribute__((ext_vector_type(8)));
typedef float f32x4 __attribute__((ext_vector_type(4)));

union BF8 { bf16x8 v; unsigned short u[8]; uint4 q; };

__device__ inline unsigned short f32_to_bf16(float f) {
    unsigned u = __builtin_bit_cast(unsigned, f);
    return (unsigned short)((u + 0x7FFFu + ((u >> 16) & 1u)) >> 16);
}
__device__ inline float bf16_lo(unsigned u) { return __builtin_bit_cast(float, u << 16); }
__device__ inline float bf16_hi(unsigned u) { return __builtin_bit_cast(float, u & 0xFFFF0000u); }
__device__ inline float relu6f(float x) { return fminf(fmaxf(x, 0.f), 6.f); }

// ---- K0: one-time prep. w1t = W1^T bf16 [192][32]; w3t = W3^T bf16 [32][192];
//      bnc = {s1*42.5[192], b1'*42.5[192], s2[192], b2'[192], s3[32], b3'[32]}
//      (42.5 = 255/6: folds the uint8 quantization of x1 into bn1)
__global__ __launch_bounds__(256) void k0_prep(
    const float* __restrict__ W1, const float* __restrict__ W3,
    const float* __restrict__ g1, const float* __restrict__ b1,
    const float* __restrict__ m1, const float* __restrict__ v1,
    const float* __restrict__ g2, const float* __restrict__ b2,
    const float* __restrict__ m2, const float* __restrict__ v2,
    const float* __restrict__ g3, const float* __restrict__ b3,
    const float* __restrict__ m3, const float* __restrict__ v3,
    unsigned short* __restrict__ w1t, unsigned short* __restrict__ w3t,
    float* __restrict__ bnc)
{
    const int gtid = blockIdx.x * 256 + threadIdx.x;
    const int gstr = gridDim.x * 256;
    for (int i = gtid; i < 6144; i += gstr) {          // w1t[n*32+k] = W1[k*192+n]
        int n = i >> 5, k = i & 31;
        w1t[i] = f32_to_bf16(W1[k * 192 + n]);
    }
    for (int i = gtid; i < 6144; i += gstr) {          // w3t[n*192+k] = W3[k*32+n]
        int n = i / 192, k = i - n * 192;
        w3t[i] = f32_to_bf16(W3[k * 32 + n]);
    }
    if (blockIdx.x == 0) {
        int t = threadIdx.x;
        const float Q = 255.f / 6.f;
        if (t < 192) {
            float s = g1[t] * rsqrtf(v1[t] + EPS);
            bnc[t] = s * Q; bnc[192 + t] = (b1[t] - m1[t] * s) * Q;
            float u = g2[t] * rsqrtf(v2[t] + EPS);
            bnc[384 + t] = u; bnc[576 + t] = b2[t] - m2[t] * u;
            if (t < 32) {
                float w = g3[t] * rsqrtf(v3[t] + EPS);
                bnc[768 + t] = w; bnc[800 + t] = b3[t] - m3[t] * w;
            }
        }
    }
}

// ---------------- K1: x1 = uint8-quant(relu6(bn1(feats @ W1))), MFMA ----------------
// 256 threads, 64 rows/block. B-frags: 12 b128 loads from L2-hot w1t.
// Epilogue: clamp(y*255/6, 0, 255) -> byte, repack via LDS, contiguous uint4 stores.
__global__ __launch_bounds__(256) void k1_expand(
    const float* __restrict__ feats, const unsigned short* __restrict__ w1t,
    const float* __restrict__ bnc, unsigned char* __restrict__ x1, int N)
{
    __shared__ __align__(16) unsigned short aT[64 * 40];     // A[r][k] bf16, stride 40
    __shared__ __align__(16) unsigned char outB[64 * 224];   // out[r][c] u8, stride 224
    const int tid = threadIdx.x;
    const int rowbase = blockIdx.x * 64;

    // stage feats tile -> bf16 A (thread: row tid/4, cols 8*(tid&3)..+7)
    {
        int r = tid >> 2, c = (tid & 3) * 8;
        int gr = rowbase + r;
        float4 f0 = {0.f,0.f,0.f,0.f}, f1 = {0.f,0.f,0.f,0.f};
        if (gr < N) {
            f0 = *(const float4*)(feats + (size_t)gr * 32 + c);
            f1 = *(const float4*)(feats + (size_t)gr * 32 + c + 4);
        }
        BF8 p;
        p.u[0] = f32_to_bf16(f0.x); p.u[1] = f32_to_bf16(f0.y);
        p.u[2] = f32_to_bf16(f0.z); p.u[3] = f32_to_bf16(f0.w);
        p.u[4] = f32_to_bf16(f1.x); p.u[5] = f32_to_bf16(f1.y);
        p.u[6] = f32_to_bf16(f1.z); p.u[7] = f32_to_bf16(f1.w);
        *(uint4*)(&aT[r * 40 + c]) = p.q;
    }
    __syncthreads();

    const int lane = tid & 63, wave = tid >> 6;
    const int m = lane & 15, q = lane >> 4;

    bf16x8 af = *(const bf16x8*)(&aT[(wave * 16 + m) * 40 + q * 8]);

    f32x4 acc[12];
#pragma unroll
    for (int t = 0; t < 12; ++t) {
        bf16x8 bf = *(const bf16x8*)(w1t + (16 * t + m) * 32 + q * 8);
        f32x4 z = {0.f, 0.f, 0.f, 0.f};
        acc[t] = __builtin_amdgcn_mfma_f32_16x16x32_bf16(af, bf, z, 0, 0, 0);
    }

    // epilogue: y*Q clamped to [0,255] -> u8  (Q folded into bnc by k0)
#pragma unroll
    for (int t = 0; t < 12; ++t) {
        int c = 16 * t + m;
        float s = bnc[c], bb = bnc[192 + c];
#pragma unroll
        for (int i = 0; i < 4; ++i) {
            int r = wave * 16 + q * 4 + i;
            float y = fmaf(acc[t][i], s, bb);
            y = fminf(fmaxf(y, 0.f), 255.f);
            outB[r * 224 + c] = (unsigned char)(y + 0.5f);
        }
    }
    __syncthreads();

    // readout: 64 rows x 12 uint4-chunks = 768, contiguous global stores
#pragma unroll
    for (int j = 0; j < 3; ++j) {
        int i = j * 256 + tid;
        int r = i / 12, c = i % 12;
        int gr = rowbase + r;
        if (gr < N)
            *(uint4*)(x1 + (size_t)gr * 192 + c * 16) = *(const uint4*)(&outB[r * 224 + c * 16]);
    }
}

// ------- K2: fused depthwise gather (u8) + bn2 + relu6 + project GEMM + bn3 + residual -------
// Phase A: 48 col-groups x 4 ch; dword gathers (4 B/lane, row = 192 B coalesced);
// 2 rows/iter -> 18 gathers in flight; byte offsets pre-multiplied; dequant folded into w2.
__global__ __launch_bounds__(192) void k2_fused(
    const unsigned char* __restrict__ x1, const int* __restrict__ nbr,
    const float* __restrict__ W2, const unsigned short* __restrict__ w3t,
    const float* __restrict__ bnc, const float* __restrict__ feats,
    float* __restrict__ out, int N)
{
    __shared__ __align__(16) unsigned short x2L[48 * 200];
    __shared__ __align__(16) int offL[48 * 12];     // byte offsets into x1; -1 = invalid
    const int tid = threadIdx.x;
    const int rowbase = blockIdx.x * 48;

    for (int i = tid; i < 432; i += 192) {
        int r = i / 9, k = i - r * 9;
        int n = rowbase + r;
        int idx = (n < N) ? nbr[(size_t)n * 9 + k] : -1;
        offL[r * 12 + k] = (idx < 0) ? -1 : idx * 192;   // 192 B per x1 row
    }

    const int cg = tid % 48;
    const int slot = tid / 48;
    const int c0 = cg * 4;
    const char* x1b = (const char*)x1 + c0;              // fold channel offset

    const float DQ = 6.f / 255.f;
    float w2v[9][4];
#pragma unroll
    for (int k = 0; k < 9; ++k) {
        float4 w = *(const float4*)(W2 + k * 192 + c0);
        w2v[k][0] = w.x * DQ; w2v[k][1] = w.y * DQ; w2v[k][2] = w.z * DQ; w2v[k][3] = w.w * DQ;
    }
    float4 s2 = *(const float4*)(bnc + 384 + c0);
    float4 bb2 = *(const float4*)(bnc + 576 + c0);
    __syncthreads();

#pragma unroll
    for (int it = 0; it < 6; ++it) {
        int r0 = it * 8 + slot, r1 = r0 + 4;
        const int* nA = &offL[r0 * 12];
        const int* nB = &offL[r1 * 12];
        int4 a03 = *(const int4*)nA; int4 a47 = *(const int4*)(nA + 4); int a8 = nA[8];
        int4 b03 = *(const int4*)nB; int4 b47 = *(const int4*)(nB + 4); int b8 = nB[8];
        int offA[9] = {a03.x, a03.y, a03.z, a03.w, a47.x, a47.y, a47.z, a47.w, a8};
        int offB[9] = {b03.x, b03.y, b03.z, b03.w, b47.x, b47.y, b47.z, b47.w, b8};
        unsigned gA[9], gB[9];
#pragma unroll
        for (int k = 0; k < 9; ++k) {
            gA[k] = *(const unsigned*)(x1b + (offA[k] < 0 ? 0 : offA[k]));
            gB[k] = *(const unsigned*)(x1b + (offB[k] < 0 ? 0 : offB[k]));
        }
        float a0 = 0.f, a1 = 0.f, a2 = 0.f, a3 = 0.f;
        float c0f = 0.f, c1 = 0.f, c2 = 0.f, c3 = 0.f;
#pragma unroll
        for (int k = 0; k < 9; ++k) {
            unsigned ga = offA[k] >= 0 ? gA[k] : 0u;     // select result, not addr
            unsigned gb = offB[k] >= 0 ? gB[k] : 0u;
            a0 = fmaf((float)(ga & 0xFF),         w2v[k][0], a0);   // v_cvt_f32_ubyte0..3
            a1 = fmaf((float)((ga >> 8) & 0xFF),  w2v[k][1], a1);
            a2 = fmaf((float)((ga >> 16) & 0xFF), w2v[k][2], a2);
            a3 = fmaf((float)(ga >> 24),          w2v[k][3], a3);
            c0f = fmaf((float)(gb & 0xFF),         w2v[k][0], c0f);
            c1  = fmaf((float)((gb >> 8) & 0xFF),  w2v[k][1], c1);
            c2  = fmaf((float)((gb >> 16) & 0xFF), w2v[k][2], c2);
            c3  = fmaf((float)(gb >> 24),          w2v[k][3], c3);
        }
        a0 = relu6f(fmaf(a0, s2.x, bb2.x));
        a1 = relu6f(fmaf(a1, s2.y, bb2.y));
        a2 = relu6f(fmaf(a2, s2.z, bb2.z));
        a3 = relu6f(fmaf(a3, s2.w, bb2.w));
        c0f = relu6f(fmaf(c0f, s2.x, bb2.x));
        c1  = relu6f(fmaf(c1,  s2.y, bb2.y));
        c2  = relu6f(fmaf(c2,  s2.z, bb2.z));
        c3  = relu6f(fmaf(c3,  s2.w, bb2.w));
        uint2 pA, pB;
        pA.x = (unsigned)f32_to_bf16(a0) | ((unsigned)f32_to_bf16(a1) << 16);
        pA.y = (unsigned)f32_to_bf16(a2) | ((unsigned)f32_to_bf16(a3) << 16);
        pB.x = (unsigned)f32_to_bf16(c0f) | ((unsigned)f32_to_bf16(c1) << 16);
        pB.y = (unsigned)f32_to_bf16(c2)  | ((unsigned)f32_to_bf16(c3) << 16);
        *(uint2*)(&x2L[r0 * 200 + c0]) = pA;
        *(uint2*)(&x2L[r1 * 200 + c0]) = pB;
    }
    __syncthreads();

    // ---- phase B: [48x192] @ [192x32] via MFMA ----
    const int lane = tid & 63;
    const int wave = tid >> 6;
    const int m = lane & 15;
    const int q = lane >> 4;

    bf16x8 bfrag[12];
#pragma unroll
    for (int s = 0; s < 6; ++s)
#pragma unroll
        for (int t = 0; t < 2; ++t)
            bfrag[s * 2 + t] = *(const bf16x8*)(w3t + (16 * t + m) * 192 + 32 * s + q * 8);

    f32x4 acc0 = {0.f, 0.f, 0.f, 0.f}, acc1 = {0.f, 0.f, 0.f, 0.f};
    const int rw = wave * 16;
#pragma unroll
    for (int s = 0; s < 6; ++s) {
        bf16x8 a = *reinterpret_cast<const bf16x8*>(&x2L[(rw + m) * 200 + 32 * s + q * 8]);
        acc0 = __builtin_amdgcn_mfma_f32_16x16x32_bf16(a, bfrag[s * 2 + 0], acc0, 0, 0, 0);
        acc1 = __builtin_amdgcn_mfma_f32_16x16x32_bf16(a, bfrag[s * 2 + 1], acc1, 0, 0, 0);
    }

#pragma unroll
    for (int t = 0; t < 2; ++t) {
        f32x4 acc = (t == 0) ? acc0 : acc1;
        int c = 16 * t + m;
        float s3 = bnc[768 + c], bb3 = bnc[800 + c];
#pragma unroll
        for (int i = 0; i < 4; ++i) {
            int r = rowbase + rw + q * 4 + i;
            if (r < N) {
                int o = r * 32 + c;
                out[o] = fmaf(acc[i], s3, bb3) + feats[o];
            }
        }
    }
}

extern "C" void kernel_launch(void* const* d_in, const int* in_sizes, int n_in,
                              void* d_out, int out_size, void* d_ws, size_t ws_size,
                              hipStream_t stream) {
    const float* feats = (const float*)d_in[0];
    const int*   nbr   = (const int*)d_in[1];
    const float* W1    = (const float*)d_in[2];
    const float* W2    = (const float*)d_in[3];
    const float* W3    = (const float*)d_in[4];
    const float* g1 = (const float*)d_in[5];
    const float* b1 = (const float*)d_in[6];
    const float* m1 = (const float*)d_in[7];
    const float* v1 = (const float*)d_in[8];
    const float* g2 = (const float*)d_in[9];
    const float* b2 = (const float*)d_in[10];
    const float* m2 = (const float*)d_in[11];
    const float* v2 = (const float*)d_in[12];
    const float* g3 = (const float*)d_in[13];
    const float* b3 = (const float*)d_in[14];
    const float* m3 = (const float*)d_in[15];
    const float* v3 = (const float*)d_in[16];
    float* out = (float*)d_out;

    const int N = in_sizes[0] / 32;

    // ws layout: x1 [N*192 u8 = 38.4 MB] | w1t [12,288 B] | w3t [12,288 B] | bnc [3,328 B]
    char* ws = (char*)d_ws;
    unsigned char*  x1  = (unsigned char*)ws;
    unsigned short* w1t = (unsigned short*)(ws + (size_t)N * 192);
    unsigned short* w3t = w1t + 6144;
    float*          bnc = (float*)(w3t + 6144);

    k0_prep<<<dim3(32), dim3(256), 0, stream>>>(
        W1, W3, g1, b1, m1, v1, g2, b2, m2, v2, g3, b3, m3, v3, w1t, w3t, bnc);
    k1_expand<<<dim3((N + 63) / 64), dim3(256), 0, stream>>>(
        feats, w1t, bnc, x1, N);
    k2_fused<<<dim3((N + 47) / 48), dim3(192), 0, stream>>>(
        x1, nbr, W2, w3t, bnc, feats, out, N);
}

// Round 6
// 196.962 us; speedup vs baseline: 2.5166x; 1.0018x over previous
//
#include <hip/hip_runtime.h>

#define EPS 1e-5f

typedef __bf16 bf16x8 __attribute__((ext_vector_type(8)));
typedef float f32x4 __attribute__((ext_vector_type(4)));

union BF8 { bf16x8 v; unsigned short u[8]; uint4 q; };

__device__ inline unsigned short f32_to_bf16(float f) {
    unsigned u = __builtin_bit_cast(unsigned, f);
    return (unsigned short)((u + 0x7FFFu + ((u >> 16) & 1u)) >> 16);
}
__device__ inline float relu6f(float x) { return fminf(fmaxf(x, 0.f), 6.f); }

// ---- K0: one-time prep. w1t = W1^T bf16 [192][32]; w3t = W3^T bf16 [32][192];
//      bnc = {s1*42.5[192], b1'*42.5[192], s2[192], b2'[192], s3[32], b3'[32]}
__global__ __launch_bounds__(256) void k0_prep(
    const float* __restrict__ W1, const float* __restrict__ W3,
    const float* __restrict__ g1, const float* __restrict__ b1,
    const float* __restrict__ m1, const float* __restrict__ v1,
    const float* __restrict__ g2, const float* __restrict__ b2,
    const float* __restrict__ m2, const float* __restrict__ v2,
    const float* __restrict__ g3, const float* __restrict__ b3,
    const float* __restrict__ m3, const float* __restrict__ v3,
    unsigned short* __restrict__ w1t, unsigned short* __restrict__ w3t,
    float* __restrict__ bnc)
{
    const int gtid = blockIdx.x * 256 + threadIdx.x;
    const int gstr = gridDim.x * 256;
    for (int i = gtid; i < 6144; i += gstr) {          // w1t[n*32+k] = W1[k*192+n]
        int n = i >> 5, k = i & 31;
        w1t[i] = f32_to_bf16(W1[k * 192 + n]);
    }
    for (int i = gtid; i < 6144; i += gstr) {          // w3t[n*192+k] = W3[k*32+n]
        int n = i / 192, k = i - n * 192;
        w3t[i] = f32_to_bf16(W3[k * 32 + n]);
    }
    if (blockIdx.x == 0) {
        int t = threadIdx.x;
        const float Q = 255.f / 6.f;
        if (t < 192) {
            float s = g1[t] * rsqrtf(v1[t] + EPS);
            bnc[t] = s * Q; bnc[192 + t] = (b1[t] - m1[t] * s) * Q;
            float u = g2[t] * rsqrtf(v2[t] + EPS);
            bnc[384 + t] = u; bnc[576 + t] = b2[t] - m2[t] * u;
            if (t < 32) {
                float w = g3[t] * rsqrtf(v3[t] + EPS);
                bnc[768 + t] = w; bnc[800 + t] = b3[t] - m3[t] * w;
            }
        }
    }
}

// ---------------- K1: x1 = uint8-quant(relu6(bn1(feats @ W1))), MFMA ----------------
// 128 rows/block, 256 threads. A-frags straight from global (wave covers 2KB contiguous),
// B-frags register-resident across 2 tiles/wave, ONE barrier (epilogue repack only).
__global__ __launch_bounds__(256) void k1_expand(
    const float* __restrict__ feats, const unsigned short* __restrict__ w1t,
    const float* __restrict__ bnc, unsigned char* __restrict__ x1, int N)
{
    __shared__ __align__(16) unsigned char outB[128 * 224];  // u8, stride 224 (14 chunks)
    const int tid = threadIdx.x;
    const int rowbase = blockIdx.x * 128;
    const int lane = tid & 63, wave = tid >> 6;
    const int m = lane & 15, q = lane >> 4;

    // B fragments once (L2-hot w1t, b128)
    bf16x8 bf[12];
#pragma unroll
    for (int t = 0; t < 12; ++t)
        bf[t] = *(const bf16x8*)(w1t + (16 * t + m) * 32 + q * 8);

    // two row-tiles per wave
#pragma unroll
    for (int p = 0; p < 2; ++p) {
        const int tile = wave * 2 + p;              // 0..7
        const int row = rowbase + tile * 16 + m;
        float4 f0 = {0.f,0.f,0.f,0.f}, f1 = {0.f,0.f,0.f,0.f};
        if (row < N) {
            f0 = *(const float4*)(feats + (size_t)row * 32 + q * 8);
            f1 = *(const float4*)(feats + (size_t)row * 32 + q * 8 + 4);
        }
        BF8 af;
        af.u[0] = f32_to_bf16(f0.x); af.u[1] = f32_to_bf16(f0.y);
        af.u[2] = f32_to_bf16(f0.z); af.u[3] = f32_to_bf16(f0.w);
        af.u[4] = f32_to_bf16(f1.x); af.u[5] = f32_to_bf16(f1.y);
        af.u[6] = f32_to_bf16(f1.z); af.u[7] = f32_to_bf16(f1.w);

        f32x4 acc[12];
#pragma unroll
        for (int t = 0; t < 12; ++t) {
            f32x4 z = {0.f, 0.f, 0.f, 0.f};
            acc[t] = __builtin_amdgcn_mfma_f32_16x16x32_bf16(af.v, bf[t], z, 0, 0, 0);
        }

        // epilogue: y*Q clamp [0,255] -> u8 into outB (Q folded into bnc)
#pragma unroll
        for (int t = 0; t < 12; ++t) {
            int c = 16 * t + m;
            float s = bnc[c], bb = bnc[192 + c];
#pragma unroll
            for (int i = 0; i < 4; ++i) {
                int r = tile * 16 + q * 4 + i;
                float y = fmaf(acc[t][i], s, bb);
                y = fminf(fmaxf(y, 0.f), 255.f);
                outB[r * 224 + c] = (unsigned char)(y + 0.5f);
            }
        }
    }
    __syncthreads();

    // readout: 128 rows x 12 uint4-chunks = 1536, contiguous global stores
#pragma unroll
    for (int j = 0; j < 6; ++j) {
        int i = j * 256 + tid;
        int r = i / 12, c = i % 12;
        int gr = rowbase + r;
        if (gr < N)
            *(uint4*)(x1 + (size_t)gr * 192 + c * 16) = *(const uint4*)(&outB[r * 224 + c * 16]);
    }
}

// ------- K2: fused depthwise gather (u8) + bn2 + relu6 + project GEMM + bn3 + residual -------
// (unchanged — at the ~3 TB/s random-gather fabric ceiling: 219 MB fetch / 78 us)
__global__ __launch_bounds__(192) void k2_fused(
    const unsigned char* __restrict__ x1, const int* __restrict__ nbr,
    const float* __restrict__ W2, const unsigned short* __restrict__ w3t,
    const float* __restrict__ bnc, const float* __restrict__ feats,
    float* __restrict__ out, int N)
{
    __shared__ __align__(16) unsigned short x2L[48 * 200];
    __shared__ __align__(16) int offL[48 * 12];
    const int tid = threadIdx.x;
    const int rowbase = blockIdx.x * 48;

    for (int i = tid; i < 432; i += 192) {
        int r = i / 9, k = i - r * 9;
        int n = rowbase + r;
        int idx = (n < N) ? nbr[(size_t)n * 9 + k] : -1;
        offL[r * 12 + k] = (idx < 0) ? -1 : idx * 192;
    }

    const int cg = tid % 48;
    const int slot = tid / 48;
    const int c0 = cg * 4;
    const char* x1b = (const char*)x1 + c0;

    const float DQ = 6.f / 255.f;
    float w2v[9][4];
#pragma unroll
    for (int k = 0; k < 9; ++k) {
        float4 w = *(const float4*)(W2 + k * 192 + c0);
        w2v[k][0] = w.x * DQ; w2v[k][1] = w.y * DQ; w2v[k][2] = w.z * DQ; w2v[k][3] = w.w * DQ;
    }
    float4 s2 = *(const float4*)(bnc + 384 + c0);
    float4 bb2 = *(const float4*)(bnc + 576 + c0);
    __syncthreads();

#pragma unroll
    for (int it = 0; it < 6; ++it) {
        int r0 = it * 8 + slot, r1 = r0 + 4;
        const int* nA = &offL[r0 * 12];
        const int* nB = &offL[r1 * 12];
        int4 a03 = *(const int4*)nA; int4 a47 = *(const int4*)(nA + 4); int a8 = nA[8];
        int4 b03 = *(const int4*)nB; int4 b47 = *(const int4*)(nB + 4); int b8 = nB[8];
        int offA[9] = {a03.x, a03.y, a03.z, a03.w, a47.x, a47.y, a47.z, a47.w, a8};
        int offB[9] = {b03.x, b03.y, b03.z, b03.w, b47.x, b47.y, b47.z, b47.w, b8};
        unsigned gA[9], gB[9];
#pragma unroll
        for (int k = 0; k < 9; ++k) {
            gA[k] = *(const unsigned*)(x1b + (offA[k] < 0 ? 0 : offA[k]));
            gB[k] = *(const unsigned*)(x1b + (offB[k] < 0 ? 0 : offB[k]));
        }
        float a0 = 0.f, a1 = 0.f, a2 = 0.f, a3 = 0.f;
        float c0f = 0.f, c1 = 0.f, c2 = 0.f, c3 = 0.f;
#pragma unroll
        for (int k = 0; k < 9; ++k) {
            unsigned ga = offA[k] >= 0 ? gA[k] : 0u;
            unsigned gb = offB[k] >= 0 ? gB[k] : 0u;
            a0 = fmaf((float)(ga & 0xFF),         w2v[k][0], a0);
            a1 = fmaf((float)((ga >> 8) & 0xFF),  w2v[k][1], a1);
            a2 = fmaf((float)((ga >> 16) & 0xFF), w2v[k][2], a2);
            a3 = fmaf((float)(ga >> 24),          w2v[k][3], a3);
            c0f = fmaf((float)(gb & 0xFF),         w2v[k][0], c0f);
            c1  = fmaf((float)((gb >> 8) & 0xFF),  w2v[k][1], c1);
            c2  = fmaf((float)((gb >> 16) & 0xFF), w2v[k][2], c2);
            c3  = fmaf((float)(gb >> 24),          w2v[k][3], c3);
        }
        a0 = relu6f(fmaf(a0, s2.x, bb2.x));
        a1 = relu6f(fmaf(a1, s2.y, bb2.y));
        a2 = relu6f(fmaf(a2, s2.z, bb2.z));
        a3 = relu6f(fmaf(a3, s2.w, bb2.w));
        c0f = relu6f(fmaf(c0f, s2.x, bb2.x));
        c1  = relu6f(fmaf(c1,  s2.y, bb2.y));
        c2  = relu6f(fmaf(c2,  s2.z, bb2.z));
        c3  = relu6f(fmaf(c3,  s2.w, bb2.w));
        uint2 pA, pB;
        pA.x = (unsigned)f32_to_bf16(a0) | ((unsigned)f32_to_bf16(a1) << 16);
        pA.y = (unsigned)f32_to_bf16(a2) | ((unsigned)f32_to_bf16(a3) << 16);
        pB.x = (unsigned)f32_to_bf16(c0f) | ((unsigned)f32_to_bf16(c1) << 16);
        pB.y = (unsigned)f32_to_bf16(c2)  | ((unsigned)f32_to_bf16(c3) << 16);
        *(uint2*)(&x2L[r0 * 200 + c0]) = pA;
        *(uint2*)(&x2L[r1 * 200 + c0]) = pB;
    }
    __syncthreads();

    const int lane = tid & 63;
    const int wave = tid >> 6;
    const int m = lane & 15;
    const int q = lane >> 4;

    bf16x8 bfrag[12];
#pragma unroll
    for (int s = 0; s < 6; ++s)
#pragma unroll
        for (int t = 0; t < 2; ++t)
            bfrag[s * 2 + t] = *(const bf16x8*)(w3t + (16 * t + m) * 192 + 32 * s + q * 8);

    f32x4 acc0 = {0.f, 0.f, 0.f, 0.f}, acc1 = {0.f, 0.f, 0.f, 0.f};
    const int rw = wave * 16;
#pragma unroll
    for (int s = 0; s < 6; ++s) {
        bf16x8 a = *reinterpret_cast<const bf16x8*>(&x2L[(rw + m) * 200 + 32 * s + q * 8]);
        acc0 = __builtin_amdgcn_mfma_f32_16x16x32_bf16(a, bfrag[s * 2 + 0], acc0, 0, 0, 0);
        acc1 = __builtin_amdgcn_mfma_f32_16x16x32_bf16(a, bfrag[s * 2 + 1], acc1, 0, 0, 0);
    }

#pragma unroll
    for (int t = 0; t < 2; ++t) {
        f32x4 acc = (t == 0) ? acc0 : acc1;
        int c = 16 * t + m;
        float s3 = bnc[768 + c], bb3 = bnc[800 + c];
#pragma unroll
        for (int i = 0; i < 4; ++i) {
            int r = rowbase + rw + q * 4 + i;
            if (r < N) {
                int o = r * 32 + c;
                out[o] = fmaf(acc[i], s3, bb3) + feats[o];
            }
        }
    }
}

extern "C" void kernel_launch(void* const* d_in, const int* in_sizes, int n_in,
                              void* d_out, int out_size, void* d_ws, size_t ws_size,
                              hipStream_t stream) {
    const float* feats = (const float*)d_in[0];
    const int*   nbr   = (const int*)d_in[1];
    const float* W1    = (const float*)d_in[2];
    const float* W2    = (const float*)d_in[3];
    const float* W3    = (const float*)d_in[4];
    const float* g1 = (const float*)d_in[5];
    const float* b1 = (const float*)d_in[6];
    const float* m1 = (const float*)d_in[7];
    const float* v1 = (const float*)d_in[8];
    const float* g2 = (const float*)d_in[9];
    const float* b2 = (const float*)d_in[10];
    const float* m2 = (const float*)d_in[11];
    const float* v2 = (const float*)d_in[12];
    const float* g3 = (const float*)d_in[13];
    const float* b3 = (const float*)d_in[14];
    const float* m3 = (const float*)d_in[15];
    const float* v3 = (const float*)d_in[16];
    float* out = (float*)d_out;

    const int N = in_sizes[0] / 32;

    // ws layout: x1 [N*192 u8 = 38.4 MB] | w1t [12,288 B] | w3t [12,288 B] | bnc [3,328 B]
    char* ws = (char*)d_ws;
    unsigned char*  x1  = (unsigned char*)ws;
    unsigned short* w1t = (unsigned short*)(ws + (size_t)N * 192);
    unsigned short* w3t = w1t + 6144;
    float*          bnc = (float*)(w3t + 6144);

    k0_prep<<<dim3(32), dim3(256), 0, stream>>>(
        W1, W3, g1, b1, m1, v1, g2, b2, m2, v2, g3, b3, m3, v3, w1t, w3t, bnc);
    k1_expand<<<dim3((N + 127) / 128), dim3(256), 0, stream>>>(
        feats, w1t, bnc, x1, N);
    k2_fused<<<dim3((N + 47) / 48), dim3(192), 0, stream>>>(
        x1, nbr, W2, w3t, bnc, feats, out, N);
}